// Round 5
// baseline (146.206 us; speedup 1.0000x reference)
//
#include <hip/hip_runtime.h>
#include <hip/hip_bf16.h>

#define NB 32
#define NP 4096
#define NM 12
#define NW 9
#define NC 64          // IN_C == OUT_C == 64
#define PN_PAD 4097
#define KDIM (NW * NC)     // 576
#define KSTEPS (KDIM / 32) // 18
#define AROW 584           // 576 + 8 pad shorts (16B-aligned rows)

#define WSW_BYTES (KDIM * NC * 2)      // 73728 B, bf16 swizzled weights
#define W2_OFFSET WSW_BYTES            // float w2d[(p*12+m)*12 + w]

typedef __attribute__((ext_vector_type(8))) short short8;
typedef __attribute__((ext_vector_type(4))) float float4v;

__device__ __forceinline__ unsigned short f32_to_bf16(float f) {
    union { float f; unsigned u; } v; v.f = f;
    unsigned r = v.u + 0x7FFFu + ((v.u >> 16) & 1u);  // RNE
    return (unsigned short)(r >> 16);
}

// Pack float4 -> 4 bf16 (round via +0x8000, take high 16 bits)
__device__ __forceinline__ uint2 pack_bf16x4(float4v v) {
    union { float f; unsigned u; } a0, a1, a2, a3;
    a0.f = v[0]; a1.f = v[1]; a2.f = v[2]; a3.f = v[3];
    unsigned u0 = a0.u + 0x8000u, u1 = a1.u + 0x8000u;
    unsigned u2 = a2.u + 0x8000u, u3 = a3.u + 0x8000u;
    uint2 r;
    r.x = __builtin_amdgcn_perm(u1, u0, 0x07060302u);  // hi16(u1)<<16 | hi16(u0)
    r.y = __builtin_amdgcn_perm(u3, u2, 0x07060302u);
    return r;
}

// Prep: (a) swizzle weights fp32 -> bf16 in MFMA B-fragment order;
//       (b) w2d[(p*12+m)*12 + w] = ww[p,m,w] * mask[p,m]  (padded stride 12)
__global__ void prep(const float* __restrict__ w,
                     const float* __restrict__ ww,
                     const float* __restrict__ mask,
                     unsigned short* __restrict__ wsw,
                     float* __restrict__ w2d) {
    int idx = blockIdx.x * 256 + threadIdx.x;
    if (idx < KDIM * NC) {
        int j    = idx & 7;
        int lane = (idx >> 3) & 63;
        int nt   = (idx >> 9) & 3;
        int ks   = idx >> 11;
        int k = ks * 32 + ((lane >> 4) * 8) + j;   // k = w*64 + i
        int n = nt * 16 + (lane & 15);             // n = o
        int wi = k >> 6;
        int ii = k & 63;
        wsw[idx] = f32_to_bf16(w[wi * (NC * NC) + n * NC + ii]);
    }
    if (idx < NP * NM * NW) {
        int wq = idx % NW;
        int pm = idx / NW;       // p*12 + m
        w2d[pm * 12 + wq] = ww[idx] * mask[pm];
    }
}

// One block (512 threads) per p.
// amdgpu_waves_per_eu(4,4): pins BOTH min and max waves/EU to 4, so the
// scheduler's register target is 512/4 = 128 VGPRs. Within that budget the
// 12 prefetched float4 gathers (48 VGPRs) + 36 accumulators stay live ->
// one latency exposure per wave instead of twelve.
// Phase 1: t[b, w*64+i] (32 x 576) fp32 -> bf16 LDS tile; thread = (b, ch-quad).
// Phase 2: 8 waves, each one 16x16 MFMA tile (mt = wid>>2, nt = wid&3).
__global__ __launch_bounds__(512)
__attribute__((amdgpu_waves_per_eu(4, 4)))
void conv_main(const float* __restrict__ x,            // (32, 4097, 64)
               const unsigned short* __restrict__ wsw, // swizzled bf16 weights
               const float* __restrict__ bias,         // (64,)
               const float* __restrict__ w2d,          // (4096, 12, 12-padded)
               const int* __restrict__ nid,            // (4096, 12)
               float* __restrict__ out)                // (32, 4096, 64)
{
    __shared__ __align__(16) unsigned short A[NB * AROW];

    const int p = blockIdx.x;
    const int tid = threadIdx.x;

    // ---- Phase 1 ----
    {
        const int i4 = tid & 15;   // float4 column within a 64-float row
        const int b  = tid >> 4;   // 0..31
        const float4v* x4 = (const float4v*)x;
        const float* w2p = w2d + p * (NM * 12);
        const int* nidp = nid + p * NM;

        int nm[NM];
        #pragma unroll
        for (int m = 0; m < NM; ++m) nm[m] = nidp[m];  // uniform -> SGPRs

        // Issue ALL 12 gather loads before any use: one latency exposure.
        float4v xv[NM];
        #pragma unroll
        for (int m = 0; m < NM; ++m)
            xv[m] = x4[(b * PN_PAD + nm[m]) * 16 + i4];

        float4v acc[NW];
        #pragma unroll
        for (int w = 0; w < NW; ++w) acc[w] = (float4v){0.f, 0.f, 0.f, 0.f};

        #pragma unroll
        for (int m = 0; m < NM; ++m) {
            #pragma unroll
            for (int w = 0; w < NW; ++w)
                acc[w] += w2p[m * 12 + w] * xv[m];
        }

        #pragma unroll
        for (int w = 0; w < NW; ++w)
            *(uint2*)&A[b * AROW + w * 64 + i4 * 4] = pack_bf16x4(acc[w]);
    }
    __syncthreads();

    // ---- Phase 2: C[32x64] = A(32x576) * B(576x64), mfma 16x16x32 bf16 ----
    {
        const int lane = tid & 63;
        const int wid  = tid >> 6;   // 0..7
        const int nt   = wid & 3;    // n-tile (16 output cols)
        const int mt   = wid >> 2;   // m-tile (16 b-rows)
        const int quad = lane >> 4;
        const int l15  = lane & 15;

        float4v acc = {0.f, 0.f, 0.f, 0.f};
        const short8* Bfrags = (const short8*)wsw;
        const int arow = mt * 16 + l15;

        #pragma unroll
        for (int ks = 0; ks < KSTEPS; ++ks) {
            short8 bfrag = Bfrags[(ks * 4 + nt) * 64 + lane];
            const short8 a = *(const short8*)&A[arow * AROW + ks * 32 + quad * 8];
            acc = __builtin_amdgcn_mfma_f32_16x16x32_bf16(a, bfrag, acc, 0, 0, 0);
        }

        const int o = nt * 16 + l15;
        const float bv = bias[o];
        #pragma unroll
        for (int reg = 0; reg < 4; ++reg) {
            const int b = mt * 16 + quad * 4 + reg;
            out[(b * NP + p) * NC + o] = acc[reg] + bv;
        }
    }
}

extern "C" void kernel_launch(void* const* d_in, const int* in_sizes, int n_in,
                              void* d_out, int out_size, void* d_ws, size_t ws_size,
                              hipStream_t stream) {
    const float* x    = (const float*)d_in[0];
    const float* w    = (const float*)d_in[1];
    const float* bias = (const float*)d_in[2];
    const float* ww   = (const float*)d_in[3];
    const int*   nid  = (const int*)d_in[4];
    const float* mask = (const float*)d_in[5];
    float* out = (float*)d_out;
    unsigned short* wsw = (unsigned short*)d_ws;
    float* w2d = (float*)((char*)d_ws + W2_OFFSET);

    const int prep_elems = NP * NM * NW;  // 442368 covers both prep jobs
    hipLaunchKernelGGL(prep, dim3((prep_elems + 255) / 256), dim3(256), 0, stream,
                       w, ww, mask, wsw, w2d);
    hipLaunchKernelGGL(conv_main, dim3(NP), dim3(512), 0, stream,
                       x, wsw, bias, w2d, nid, out);
}

// Round 6
// 145.477 us; speedup vs baseline: 1.0050x; 1.0050x over previous
//
#include <hip/hip_runtime.h>
#include <hip/hip_bf16.h>

#define NB 32
#define NP 4096
#define NM 12
#define NW 9
#define NC 64          // IN_C == OUT_C == 64
#define PN_PAD 4097
#define KDIM (NW * NC)     // 576
#define KSTEPS (KDIM / 32) // 18
#define AROW 584           // 576 + 8 pad shorts (16B-aligned rows)

#define WSW_BYTES (KDIM * NC * 2)      // 73728 B, bf16 swizzled weights
#define W2_OFFSET WSW_BYTES            // float w2d[(p*12+m)*12 + w]

typedef __attribute__((ext_vector_type(8))) short short8;
typedef __attribute__((ext_vector_type(4))) float float4v;

// async global->LDS DMA, 16 B per lane; LDS dest = wave-uniform base + lane*16
#define GLD_LDS16(g, l) __builtin_amdgcn_global_load_lds( \
    (const __attribute__((address_space(1))) unsigned int*)(g), \
    (__attribute__((address_space(3))) unsigned int*)(l), 16, 0, 0)

__device__ __forceinline__ unsigned short f32_to_bf16(float f) {
    union { float f; unsigned u; } v; v.f = f;
    unsigned r = v.u + 0x7FFFu + ((v.u >> 16) & 1u);  // RNE
    return (unsigned short)(r >> 16);
}

// Pack float4 -> 4 bf16 (round via +0x8000, take high 16 bits)
__device__ __forceinline__ uint2 pack_bf16x4(float4v v) {
    union { float f; unsigned u; } a0, a1, a2, a3;
    a0.f = v[0]; a1.f = v[1]; a2.f = v[2]; a3.f = v[3];
    unsigned u0 = a0.u + 0x8000u, u1 = a1.u + 0x8000u;
    unsigned u2 = a2.u + 0x8000u, u3 = a3.u + 0x8000u;
    uint2 r;
    r.x = __builtin_amdgcn_perm(u1, u0, 0x07060302u);  // hi16(u1)<<16 | hi16(u0)
    r.y = __builtin_amdgcn_perm(u3, u2, 0x07060302u);
    return r;
}

// Prep: (a) swizzle weights fp32 -> bf16 in MFMA B-fragment order;
//       (b) w2d[(p*12+m)*12 + w] = ww[p,m,w] * mask[p,m]  (padded stride 12)
__global__ void prep(const float* __restrict__ w,
                     const float* __restrict__ ww,
                     const float* __restrict__ mask,
                     unsigned short* __restrict__ wsw,
                     float* __restrict__ w2d) {
    int idx = blockIdx.x * 256 + threadIdx.x;
    if (idx < KDIM * NC) {
        int j    = idx & 7;
        int lane = (idx >> 3) & 63;
        int nt   = (idx >> 9) & 3;
        int ks   = idx >> 11;
        int k = ks * 32 + ((lane >> 4) * 8) + j;   // k = w*64 + i
        int n = nt * 16 + (lane & 15);             // n = o
        int wi = k >> 6;
        int ii = k & 63;
        wsw[idx] = f32_to_bf16(w[wi * (NC * NC) + n * NC + ii]);
    }
    if (idx < NP * NM * NW) {
        int wq = idx % NW;
        int pm = idx / NW;       // p*12 + m
        w2d[pm * 12 + wq] = ww[idx] * mask[pm];
    }
}

// One block (512 threads) per p.
// Gather path uses global_load_lds DMA (zero VGPR dependency): 4 quarters of
// 3 m-values each; per quarter each wave issues 3 fire-and-forget DMAs into a
// 24.6 KB LDS stage, barrier, consume into 36 persistent fp32 accumulators.
// A-tile (37.4 KB bf16) ALIASES the stage buffer (written after last consume).
// Phase 2: 8 waves, each one 16x16 MFMA tile (mt = wid>>2, nt = wid&3).
__global__ __launch_bounds__(512)
void conv_main(const float* __restrict__ x,            // (32, 4097, 64)
               const unsigned short* __restrict__ wsw, // swizzled bf16 weights
               const float* __restrict__ bias,         // (64,)
               const float* __restrict__ w2d,          // (4096, 12, 12-padded)
               const int* __restrict__ nid,            // (4096, 12)
               float* __restrict__ out)                // (32, 4096, 64)
{
    // Aliased buffer: [0, 24576) = x stage (3 m * 32 b * 256 B rows),
    // then reused as bf16 A-tile (NB * AROW * 2 = 37376 B).
    __shared__ __align__(16) unsigned char BUF[NB * AROW * 2];

    const int p = blockIdx.x;
    const int tid = threadIdx.x;
    const int lane = tid & 63;
    const int wid  = tid >> 6;   // 0..7

    const float* w2p = w2d + p * (NM * 12);
    const int* nidp = nid + p * NM;

    int nm[NM];
    #pragma unroll
    for (int m = 0; m < NM; ++m) nm[m] = nidp[m];  // uniform -> SGPRs

    const int b  = tid >> 4;   // 0..31  (consumer mapping)
    const int i4 = tid & 15;   // float4 column

    float4v acc[NW];
    #pragma unroll
    for (int w = 0; w < NW; ++w) acc[w] = (float4v){0.f, 0.f, 0.f, 0.f};

    #pragma unroll
    for (int Q = 0; Q < 4; ++Q) {
        // ---- issue DMA: 24 wave-instructions, 3 per wave ----
        #pragma unroll
        for (int j = 0; j < 3; ++j) {
            const int I  = wid + 8 * j;   // 0..23, wave-uniform
            const int ml = I >> 3;        // local m 0..2
            const int q  = I & 7;         // b-quad 0..7
            const int m  = Q * 3 + ml;
            const int brow = q * 4 + (lane >> 4);
            const float* gsrc = x + ((size_t)(brow * PN_PAD + nm[m])) * 64
                                  + (lane & 15) * 4;
            unsigned char* ldst = BUF + (ml * 32 + q * 4) * 256;  // uniform base
            GLD_LDS16(gsrc, ldst);
        }
        __syncthreads();  // drains vmcnt, DMA data visible to all waves

        // ---- consume: 3 ds_read_b128 + 27 float4-FMAs per thread ----
        #pragma unroll
        for (int ml = 0; ml < 3; ++ml) {
            const float4v xv = *(const float4v*)(BUF + (ml * 32 + b) * 256 + i4 * 16);
            const int m = Q * 3 + ml;
            #pragma unroll
            for (int w = 0; w < NW; ++w)
                acc[w] += w2p[m * 12 + w] * xv;
        }
        __syncthreads();  // stage fully consumed; safe to overwrite
    }

    // ---- write bf16 A-tile into (aliased) BUF ----
    unsigned short* A = (unsigned short*)BUF;
    #pragma unroll
    for (int w = 0; w < NW; ++w)
        *(uint2*)&A[b * AROW + w * 64 + i4 * 4] = pack_bf16x4(acc[w]);
    __syncthreads();

    // ---- Phase 2: C[32x64] = A(32x576) * B(576x64), mfma 16x16x32 bf16 ----
    {
        const int nt   = wid & 3;    // n-tile (16 output cols)
        const int mt   = wid >> 2;   // m-tile (16 b-rows)
        const int quad = lane >> 4;
        const int l15  = lane & 15;

        float4v cacc = {0.f, 0.f, 0.f, 0.f};
        const short8* Bfrags = (const short8*)wsw;
        const int arow = mt * 16 + l15;

        #pragma unroll
        for (int ks = 0; ks < KSTEPS; ++ks) {
            short8 bfrag = Bfrags[(ks * 4 + nt) * 64 + lane];
            const short8 a = *(const short8*)&A[arow * AROW + ks * 32 + quad * 8];
            cacc = __builtin_amdgcn_mfma_f32_16x16x32_bf16(a, bfrag, cacc, 0, 0, 0);
        }

        const int o = nt * 16 + l15;
        const float bv = bias[o];
        #pragma unroll
        for (int reg = 0; reg < 4; ++reg) {
            const int bb = mt * 16 + quad * 4 + reg;
            out[(bb * NP + p) * NC + o] = cacc[reg] + bv;
        }
    }
}

extern "C" void kernel_launch(void* const* d_in, const int* in_sizes, int n_in,
                              void* d_out, int out_size, void* d_ws, size_t ws_size,
                              hipStream_t stream) {
    const float* x    = (const float*)d_in[0];
    const float* w    = (const float*)d_in[1];
    const float* bias = (const float*)d_in[2];
    const float* ww   = (const float*)d_in[3];
    const int*   nid  = (const int*)d_in[4];
    const float* mask = (const float*)d_in[5];
    float* out = (float*)d_out;
    unsigned short* wsw = (unsigned short*)d_ws;
    float* w2d = (float*)((char*)d_ws + W2_OFFSET);

    const int prep_elems = NP * NM * NW;  // 442368 covers both prep jobs
    hipLaunchKernelGGL(prep, dim3((prep_elems + 255) / 256), dim3(256), 0, stream,
                       w, ww, mask, wsw, w2d);
    hipLaunchKernelGGL(conv_main, dim3(NP), dim3(512), 0, stream,
                       x, wsw, bias, w2d, nid, out);
}

// Round 7
// 137.640 us; speedup vs baseline: 1.0622x; 1.0569x over previous
//
#include <hip/hip_runtime.h>
#include <hip/hip_bf16.h>

#define NB 32
#define NP 4096
#define NM 12
#define NW 9
#define NC 64          // IN_C == OUT_C == 64
#define PN_PAD 4097
#define KDIM (NW * NC)     // 576
#define KSTEPS (KDIM / 32) // 18
#define AROW 584           // 576 + 8 pad shorts (16B-aligned rows)

#define WSW_BYTES (KDIM * NC * 2)            // 73728 B  bf16 swizzled weights
#define W2_OFFSET WSW_BYTES
#define W2_BYTES (NP * NM * 12 * 4)          // 2359296 B  w2d
#define XB_OFFSET (W2_OFFSET + W2_BYTES)     // 2433024
#define XB_BYTES (NB * PN_PAD * NC * 2)      // 16781312 B  bf16 x
#define WS_NEED ((size_t)XB_OFFSET + XB_BYTES)

typedef __attribute__((ext_vector_type(8))) short short8;
typedef __attribute__((ext_vector_type(4))) float float4v;

__device__ __forceinline__ unsigned short f32_to_bf16(float f) {
    union { float f; unsigned u; } v; v.f = f;
    unsigned r = v.u + 0x7FFFu + ((v.u >> 16) & 1u);  // RNE
    return (unsigned short)(r >> 16);
}

// Pack float4 -> 4 bf16 (round via +0x8000, take high 16 bits)
__device__ __forceinline__ uint2 pack_bf16x4(float4v v) {
    union { float f; unsigned u; } a0, a1, a2, a3;
    a0.f = v[0]; a1.f = v[1]; a2.f = v[2]; a3.f = v[3];
    unsigned u0 = a0.u + 0x8000u, u1 = a1.u + 0x8000u;
    unsigned u2 = a2.u + 0x8000u, u3 = a3.u + 0x8000u;
    uint2 r;
    r.x = __builtin_amdgcn_perm(u1, u0, 0x07060302u);
    r.y = __builtin_amdgcn_perm(u3, u2, 0x07060302u);
    return r;
}

// 4 packed bf16 -> float4 (bf16->f32 is a 16-bit left shift)
__device__ __forceinline__ float4v bf16x4_to_f32(uint2 u) {
    union { unsigned u; float f; } c0, c1, c2, c3;
    c0.u = u.x << 16; c1.u = u.x & 0xFFFF0000u;
    c2.u = u.y << 16; c3.u = u.y & 0xFFFF0000u;
    return (float4v){c0.f, c1.f, c2.f, c3.f};
}

// Prep: (a) swizzle weights fp32 -> bf16 in MFMA B-fragment order;
//       (b) w2d[(p*12+m)*12 + w] = ww[p,m,w] * mask[p,m]
__global__ void prep(const float* __restrict__ w,
                     const float* __restrict__ ww,
                     const float* __restrict__ mask,
                     unsigned short* __restrict__ wsw,
                     float* __restrict__ w2d) {
    int idx = blockIdx.x * 256 + threadIdx.x;
    if (idx < KDIM * NC) {
        int j    = idx & 7;
        int lane = (idx >> 3) & 63;
        int nt   = (idx >> 9) & 3;
        int ks   = idx >> 11;
        int k = ks * 32 + ((lane >> 4) * 8) + j;   // k = w*64 + i
        int n = nt * 16 + (lane & 15);             // n = o
        int wi = k >> 6;
        int ii = k & 63;
        wsw[idx] = f32_to_bf16(w[wi * (NC * NC) + n * NC + ii]);
    }
    if (idx < NP * NM * NW) {
        int wq = idx % NW;
        int pm = idx / NW;       // p*12 + m
        w2d[pm * 12 + wq] = ww[idx] * mask[pm];
    }
}

// Convert x (fp32) -> bf16 rows in workspace. 2097664 float4 groups.
__global__ void prep_x(const float* __restrict__ x,
                       unsigned short* __restrict__ xb) {
    int idx = blockIdx.x * 256 + threadIdx.x;
    const int n4 = NB * PN_PAD * NC / 4;  // 2097664
    if (idx < n4) {
        const float4v* x4 = (const float4v*)x;
        ((uint2*)xb)[idx] = pack_bf16x4(x4[idx]);
    }
}

// One block (512 threads) per p; gathers from BF16 x (half the L2-miss bytes).
// Phase 1: t[b, w*64+i] (32 x 576) fp32 acc -> bf16 LDS tile; thread=(b, ch-quad).
// Phase 2: 8 waves, each one 16x16 MFMA tile.
__global__ __launch_bounds__(512)
void conv_main_bf16(const float* __restrict__ x,            // unused (kept for symmetry)
                    const unsigned short* __restrict__ xb,  // (32, 4097, 64) bf16
                    const unsigned short* __restrict__ wsw,
                    const float* __restrict__ bias,
                    const float* __restrict__ w2d,
                    const int* __restrict__ nid,
                    float* __restrict__ out) {
    __shared__ __align__(16) unsigned short A[NB * AROW];

    const int p = blockIdx.x;
    const int tid = threadIdx.x;

    // ---- Phase 1 ----
    {
        const int i4 = tid & 15;   // 4-channel group within the 64-ch row
        const int b  = tid >> 4;   // 0..31
        const uint2* xb2 = (const uint2*)xb;   // row = 16 uint2 (128 B)
        const float* w2p = w2d + p * (NM * 12);
        const int* nidp = nid + p * NM;

        int nm[NM];
        #pragma unroll
        for (int m = 0; m < NM; ++m) nm[m] = nidp[m];  // uniform -> SGPRs

        uint2 xv[NM];
        #pragma unroll
        for (int m = 0; m < NM; ++m)
            xv[m] = xb2[(b * PN_PAD + nm[m]) * 16 + i4];

        float4v acc[NW];
        #pragma unroll
        for (int w = 0; w < NW; ++w) acc[w] = (float4v){0.f, 0.f, 0.f, 0.f};

        #pragma unroll
        for (int m = 0; m < NM; ++m) {
            const float4v xf = bf16x4_to_f32(xv[m]);
            #pragma unroll
            for (int w = 0; w < NW; ++w)
                acc[w] += w2p[m * 12 + w] * xf;
        }

        #pragma unroll
        for (int w = 0; w < NW; ++w)
            *(uint2*)&A[b * AROW + w * 64 + i4 * 4] = pack_bf16x4(acc[w]);
    }
    __syncthreads();

    // ---- Phase 2 ----
    {
        const int lane = tid & 63;
        const int wid  = tid >> 6;
        const int nt   = wid & 3;
        const int mt   = wid >> 2;
        const int quad = lane >> 4;
        const int l15  = lane & 15;

        float4v acc = {0.f, 0.f, 0.f, 0.f};
        const short8* Bfrags = (const short8*)wsw;
        const int arow = mt * 16 + l15;

        #pragma unroll
        for (int ks = 0; ks < KSTEPS; ++ks) {
            short8 bfrag = Bfrags[(ks * 4 + nt) * 64 + lane];
            const short8 a = *(const short8*)&A[arow * AROW + ks * 32 + quad * 8];
            acc = __builtin_amdgcn_mfma_f32_16x16x32_bf16(a, bfrag, acc, 0, 0, 0);
        }

        const int o = nt * 16 + l15;
        const float bv = bias[o];
        #pragma unroll
        for (int reg = 0; reg < 4; ++reg) {
            const int b = mt * 16 + quad * 4 + reg;
            out[(b * NP + p) * NC + o] = acc[reg] + bv;
        }
    }
}

// Fallback (fp32 gather, R4 structure) if workspace is too small for xb.
__global__ __launch_bounds__(512)
void conv_main_fp32(const float* __restrict__ x,
                    const unsigned short* __restrict__ wsw,
                    const float* __restrict__ bias,
                    const float* __restrict__ w2d,
                    const int* __restrict__ nid,
                    float* __restrict__ out) {
    __shared__ __align__(16) unsigned short A[NB * AROW];
    const int p = blockIdx.x;
    const int tid = threadIdx.x;
    {
        const int i4 = tid & 15;
        const int b  = tid >> 4;
        const float4v* x4 = (const float4v*)x;
        const float* w2p = w2d + p * (NM * 12);
        const int* nidp = nid + p * NM;
        int nm[NM];
        #pragma unroll
        for (int m = 0; m < NM; ++m) nm[m] = nidp[m];
        float4v xv[NM];
        #pragma unroll
        for (int m = 0; m < NM; ++m)
            xv[m] = x4[(b * PN_PAD + nm[m]) * 16 + i4];
        float4v acc[NW];
        #pragma unroll
        for (int w = 0; w < NW; ++w) acc[w] = (float4v){0.f, 0.f, 0.f, 0.f};
        #pragma unroll
        for (int m = 0; m < NM; ++m) {
            #pragma unroll
            for (int w = 0; w < NW; ++w)
                acc[w] += w2p[m * 12 + w] * xv[m];
        }
        #pragma unroll
        for (int w = 0; w < NW; ++w)
            *(uint2*)&A[b * AROW + w * 64 + i4 * 4] = pack_bf16x4(acc[w]);
    }
    __syncthreads();
    {
        const int lane = tid & 63;
        const int wid  = tid >> 6;
        const int nt   = wid & 3;
        const int mt   = wid >> 2;
        const int quad = lane >> 4;
        const int l15  = lane & 15;
        float4v acc = {0.f, 0.f, 0.f, 0.f};
        const short8* Bfrags = (const short8*)wsw;
        const int arow = mt * 16 + l15;
        #pragma unroll
        for (int ks = 0; ks < KSTEPS; ++ks) {
            short8 bfrag = Bfrags[(ks * 4 + nt) * 64 + lane];
            const short8 a = *(const short8*)&A[arow * AROW + ks * 32 + quad * 8];
            acc = __builtin_amdgcn_mfma_f32_16x16x32_bf16(a, bfrag, acc, 0, 0, 0);
        }
        const int o = nt * 16 + l15;
        const float bv = bias[o];
        #pragma unroll
        for (int reg = 0; reg < 4; ++reg) {
            const int b = mt * 16 + quad * 4 + reg;
            out[(b * NP + p) * NC + o] = acc[reg] + bv;
        }
    }
}

extern "C" void kernel_launch(void* const* d_in, const int* in_sizes, int n_in,
                              void* d_out, int out_size, void* d_ws, size_t ws_size,
                              hipStream_t stream) {
    const float* x    = (const float*)d_in[0];
    const float* w    = (const float*)d_in[1];
    const float* bias = (const float*)d_in[2];
    const float* ww   = (const float*)d_in[3];
    const int*   nid  = (const int*)d_in[4];
    const float* mask = (const float*)d_in[5];
    float* out = (float*)d_out;
    unsigned short* wsw = (unsigned short*)d_ws;
    float* w2d = (float*)((char*)d_ws + W2_OFFSET);
    unsigned short* xb = (unsigned short*)((char*)d_ws + XB_OFFSET);

    const int prep_elems = NP * NM * NW;  // 442368 covers both prep jobs
    hipLaunchKernelGGL(prep, dim3((prep_elems + 255) / 256), dim3(256), 0, stream,
                       w, ww, mask, wsw, w2d);
    if (ws_size >= WS_NEED) {
        const int n4 = NB * PN_PAD * NC / 4;  // 2097664
        hipLaunchKernelGGL(prep_x, dim3((n4 + 255) / 256), dim3(256), 0, stream,
                           x, xb);
        hipLaunchKernelGGL(conv_main_bf16, dim3(NP), dim3(512), 0, stream,
                           x, xb, wsw, bias, w2d, nid, out);
    } else {
        hipLaunchKernelGGL(conv_main_fp32, dim3(NP), dim3(512), 0, stream,
                           x, wsw, bias, w2d, nid, out);
    }
}